// Round 4
// baseline (466.019 us; speedup 1.0000x reference)
//
#include <hip/hip_runtime.h>

// Problem constants
#define Bz 16      // batch
#define Tin 12     // T_IN
#define Ttot 24    // T_TOTAL
#define NN 5000    // nodes
#define Cc 4       // channels
#define KK 16      // neighbors
#define HH 4       // heads
#define OO 12      // T_TOTAL - T_IN
#define TH 48      // Tin * HH
#define BT 192     // Bz * Tin
#define G  8       // bt-groups (2 batches each) == number of XCDs
#define JJ 24      // (b,t) pairs per group

// DIAGNOSTIC ROUND: both kernels loop their body `reps` times (runtime arg,
// idempotent work) so their dispatches exceed the 44us fill cutoff and become
// visible in rocprof top-5 with full counters. reps=16 this round.

// Native clang vector for nontemporal builtins (HIP float4 is a class type
// the builtin rejects). Same size/alignment as float4.
typedef float nfloat4 __attribute__((ext_vector_type(4)));

__device__ __forceinline__ float4 nt_load4(const float4* p) {
    nfloat4 v = __builtin_nontemporal_load((const nfloat4*)p);
    return *(float4*)&v;
}
__device__ __forceinline__ void nt_store4(float4 v, float4* p) {
    __builtin_nontemporal_store(*(nfloat4*)&v, (nfloat4*)p);
}

// ============ kernel 1: transpose x -> xT2(g, N, 24) + concat copy ==========
#define K1_NB 64   // nodes per tile
#define K1_BT 24   // (b,t) pairs per tile == JJ (one group per tile row)

__global__ __launch_bounds__(256) void transpose_concat_kernel(
    const float4* __restrict__ x4,   // (BT, N)
    float4* __restrict__ xT2,        // (G, N, JJ)
    float4* __restrict__ out4,       // (B*Ttot, N)
    int reps)
{
    __shared__ float4 tile[K1_BT][K1_NB + 1];
    const int n0  = blockIdx.x * K1_NB;
    const int g   = blockIdx.y;           // group == bt-tile
    const int bt0 = g * K1_BT;
    const int rem = min(K1_NB, NN - n0);
    const int tid = threadIdx.x;

    for (int rep = 0; rep < reps; ++rep) {
        #pragma unroll
        for (int r = 0; r < (K1_NB * K1_BT) / 256; r++) {
            int tau = r * 256 + tid;
            int j = tau / K1_NB;              // bt within tile
            int i = tau % K1_NB;              // node (lane-consecutive)
            if (i < rem) {
                int bt = bt0 + j;
                float4 v = nt_load4(&x4[(size_t)bt * NN + n0 + i]);
                tile[j][i] = v;
                int b = bt / Tin, t = bt - b * Tin;
                nt_store4(v, &out4[(size_t)(b * Ttot + t) * NN + n0 + i]);
            }
        }
        __syncthreads();

        #pragma unroll
        for (int r = 0; r < (K1_NB * K1_BT) / 256; r++) {
            int tau = r * 256 + tid;
            int i = tau / K1_BT;              // node
            int j = tau - i * K1_BT;          // j within group (lane-consecutive)
            if (i < rem) {
                xT2[((size_t)g * NN + (n0 + i)) * JJ + j] = tile[j][i];
            }
        }
        __syncthreads();                      // tile reuse guard across reps
    }
}

// ============ kernel 2: per-(g, node-block) gather + aggregate + GEMM =======
#define NPB 8                  // nodes per block (5000 = 625 * 8, exact)
#define FST 5                  // per-t   (4 heads + 1 pad)
#define FSB 61                 // per-b_l (12*5 + 1)
#define FSN 123                // per-nl  (2*61 + 1)

__global__ __launch_bounds__(192) void gnn_main_kernel(
    const float4* __restrict__ xT2,   // (G, N, JJ)
    const float* __restrict__ dists,  // (N, K)
    const float* __restrict__ W,      // (48, 12)
    const float* __restrict__ bias,   // (12,)
    const int*   __restrict__ nbrs,   // (N, K)
    float4* __restrict__ out4,        // (B*Ttot, N)
    int reps)
{
    __shared__ float4 feat[NPB * FSN];      // 15.7 KB
    __shared__ float4 w4_s[NPB][KK];        // gaussian weights, [nl][k] = 4 heads
    __shared__ float  W_s[TH * OO];
    __shared__ float  bias_s[OO];
    __shared__ int    nbroff_s[NPB][KK];    // pre-scaled BYTE offsets: nbr*384

    const int bid = blockIdx.x;
    const int g   = bid & 7;                 // XCD-pin heuristic (locality only)
    const int n0  = (bid >> 3) * NPB;
    const int tid = threadIdx.x;

    for (int rep = 0; rep < reps; ++rep) {
        // ---- stage small tensors ----
        for (int i = tid; i < TH * OO; i += 192) W_s[i] = W[i];
        if (tid < OO) bias_s[tid] = bias[tid];
        if (tid < NPB * KK) {
            int nl = tid >> 4, k = tid & 15;
            nbroff_s[nl][k] = nbrs[(n0 + nl) * KK + k] * (JJ * (int)sizeof(float4));
            float d = dists[(n0 + nl) * KK + k];
            float p = expf(-(d * d) * (1.0f / 144.0f));
            float4 wv;
            wv.x = p;
            wv.y = p * p;
            wv.z = wv.y * p;
            wv.w = wv.y * wv.y;
            w4_s[nl][k] = wv;
        }
        __syncthreads();

        // ---- phase A: gather (384 B contiguous per neighbor row) + aggregate
        {
            const int nl  = tid / JJ;            // 0..7
            const int j   = tid - nl * JJ;       // 0..23 (lane-consecutive)
            const int b_l = j / Tin;             // 0..1
            const int t   = j - b_l * Tin;       // 0..11
            const char* xgb = (const char*)xT2 + (size_t)g * (NN * JJ * sizeof(float4));
            const unsigned j16 = (unsigned)j * (unsigned)sizeof(float4);

            float4 a0 = {0,0,0,0}, a1 = {0,0,0,0}, a2 = {0,0,0,0}, a3 = {0,0,0,0};
            #pragma unroll
            for (int k = 0; k < KK; k++) {
                unsigned off = (unsigned)nbroff_s[nl][k] + j16;
                float4 xv = *(const float4*)(xgb + off);
                float4 wv = w4_s[nl][k];
                a0.x += wv.x * xv.x; a0.y += wv.x * xv.y; a0.z += wv.x * xv.z; a0.w += wv.x * xv.w;
                a1.x += wv.y * xv.x; a1.y += wv.y * xv.y; a1.z += wv.y * xv.z; a1.w += wv.y * xv.w;
                a2.x += wv.z * xv.x; a2.y += wv.z * xv.y; a2.z += wv.z * xv.z; a2.w += wv.z * xv.w;
                a3.x += wv.w * xv.x; a3.y += wv.w * xv.y; a3.z += wv.w * xv.z; a3.w += wv.w * xv.w;
            }
            const int base = nl * FSN + b_l * FSB + t * FST;
            feat[base + 0] = a0;
            feat[base + 1] = a1;
            feat[base + 2] = a2;
            feat[base + 3] = a3;
        }
        __syncthreads();

        // ---- phase B: (48 -> 12) GEMM + bias + ReLU ----
        {
            const int nl  = tid & 7;             // lane-consecutive -> 1 full line
            const int bo  = tid >> 3;            // 0..23
            const int b_l = bo / OO;             // 0..1
            const int o   = bo - b_l * OO;       // 0..11
            const float bz = bias_s[o];
            float4 acc = {bz, bz, bz, bz};
            const int fbase = nl * FSN + b_l * FSB;
            #pragma unroll
            for (int t = 0; t < Tin; t++) {
                #pragma unroll
                for (int h = 0; h < HH; h++) {
                    float  wv = W_s[(t * HH + h) * OO + o];
                    float4 f  = feat[fbase + t * FST + h];
                    acc.x += wv * f.x; acc.y += wv * f.y;
                    acc.z += wv * f.z; acc.w += wv * f.w;
                }
            }
            acc.x = fmaxf(acc.x, 0.0f); acc.y = fmaxf(acc.y, 0.0f);
            acc.z = fmaxf(acc.z, 0.0f); acc.w = fmaxf(acc.w, 0.0f);
            const int b = g * 2 + b_l;
            nt_store4(acc, &out4[(size_t)(b * Ttot + Tin + o) * NN + n0 + nl]);
        }
        __syncthreads();                         // LDS reuse guard across reps
    }
}

extern "C" void kernel_launch(void* const* d_in, const int* in_sizes, int n_in,
                              void* d_out, int out_size, void* d_ws, size_t ws_size,
                              hipStream_t stream) {
    const float* x     = (const float*)d_in[0];
    const float* dists = (const float*)d_in[1];
    const float* W     = (const float*)d_in[2];
    const float* bias  = (const float*)d_in[3];
    const int*   nbrs  = (const int*)d_in[4];
    float4* out4 = (float4*)d_out;
    float4* xT2  = (float4*)d_ws;     // G*NN*JJ*16 B = 15.36 MB of ws

    const int reps = 16;              // DIAGNOSTIC: x16 both kernels

    dim3 g1((NN + K1_NB - 1) / K1_NB, G);          // (79, 8)
    hipLaunchKernelGGL(transpose_concat_kernel, g1, dim3(256), 0, stream,
                       (const float4*)x, xT2, out4, reps);

    hipLaunchKernelGGL(gnn_main_kernel, dim3((NN / NPB) * G), dim3(192), 0, stream,
                       (const float4*)xT2, dists, W, bias, nbrs, out4, reps);
}

// Round 5
// 106.829 us; speedup vs baseline: 4.3623x; 4.3623x over previous
//
#include <hip/hip_runtime.h>

// Problem constants
#define Bz 16      // batch
#define Tin 12     // T_IN
#define Ttot 24    // T_TOTAL
#define NN 5000    // nodes
#define Cc 4       // channels
#define KK 16      // neighbors
#define HH 4       // heads
#define OO 12      // T_TOTAL - T_IN
#define TH 48      // Tin * HH
#define BT 192     // Bz * Tin
#define G  8       // bt-groups (2 batches each) == number of XCDs
#define JJ 24      // (b,t) pairs per group

// Native clang vectors (HIP float4 is a class type the builtins reject).
typedef float nfloat4 __attribute__((ext_vector_type(4)));
typedef float f2 __attribute__((ext_vector_type(2)));   // packed-math pairs

__device__ __forceinline__ float4 nt_load4(const float4* p) {
    nfloat4 v = __builtin_nontemporal_load((const nfloat4*)p);
    return *(float4*)&v;
}
__device__ __forceinline__ void nt_store4(float4 v, float4* p) {
    __builtin_nontemporal_store(*(nfloat4*)&v, (nfloat4*)p);
}

// ============ kernel 1: transpose x -> xT2(g, N, 24) + concat copy ==========
#define K1_NB 64   // nodes per tile
#define K1_BT 24   // (b,t) pairs per tile == JJ

__global__ __launch_bounds__(256) void transpose_concat_kernel(
    const float4* __restrict__ x4,   // (BT, N)
    float4* __restrict__ xT2,        // (G, N, JJ)
    float4* __restrict__ out4)       // (B*Ttot, N)
{
    __shared__ float4 tile[K1_BT][K1_NB + 1];
    const int n0  = blockIdx.x * K1_NB;
    const int g   = blockIdx.y;
    const int bt0 = g * K1_BT;
    const int rem = min(K1_NB, NN - n0);
    const int tid = threadIdx.x;

    #pragma unroll
    for (int r = 0; r < (K1_NB * K1_BT) / 256; r++) {
        int tau = r * 256 + tid;
        int j = tau / K1_NB;
        int i = tau % K1_NB;
        if (i < rem) {
            int bt = bt0 + j;
            float4 v = nt_load4(&x4[(size_t)bt * NN + n0 + i]);
            tile[j][i] = v;
            int b = bt / Tin, t = bt - b * Tin;
            nt_store4(v, &out4[(size_t)(b * Ttot + t) * NN + n0 + i]);
        }
    }
    __syncthreads();

    // xT2 IS re-read by kernel 2 -> regular (allocating) store.
    #pragma unroll
    for (int r = 0; r < (K1_NB * K1_BT) / 256; r++) {
        int tau = r * 256 + tid;
        int i = tau / K1_BT;
        int j = tau - i * K1_BT;
        if (i < rem) {
            xT2[((size_t)g * NN + (n0 + i)) * JJ + j] = tile[j][i];
        }
    }
}

// ============ kernel 2: per-(g, node-block) gather + aggregate + GEMM =======
// grid.x = 625*8; g = blockIdx.x % 8 -> XCD-pinned (locality heuristic only).
#define NPB 8                  // nodes per block
// Compact feat layout (float4 units): L = nl*FSN2 + b_l*FSB2 + h*12 + t
//  - phase-B read (t,h uniform per instr): group = 3*nl mod 8 -> all 8 distinct
//  - phase-A write (h uniform): ~3-way spread over (b_l + t) -> near-free
#define FSB2 49
#define FSN2 99                // 2*49 + 1
#define WTS  52                // Wt_s row stride in floats (13 odd -> spread)

__global__ __launch_bounds__(192) void gnn_main_kernel(
    const float4* __restrict__ xT2,   // (G, N, JJ)
    const float* __restrict__ dists,  // (N, K)
    const float* __restrict__ W,      // (48, 12)
    const float* __restrict__ bias,   // (12,)
    const int*   __restrict__ nbrs,   // (N, K)
    float4* __restrict__ out4)        // (B*Ttot, N)
{
    __shared__ float4 feat[NPB * FSN2];     // 12.4 KB
    __shared__ float4 w4_s[NPB][KK + 1];    // +1 f4 pad: kills 3-way read conflict
    __shared__ float  Wt_s[OO * WTS];       // W transposed: Wt[o][t*4+h], padded
    __shared__ float  bias_s[OO];
    __shared__ int    nbroff_s[NPB][KK + 1];// pre-scaled BYTE offsets: nbr*384

    const int bid = blockIdx.x;
    const int g   = bid & 7;
    const int n0  = (bid >> 3) * NPB;
    const int tid = threadIdx.x;

    // ---- stage small tensors ----
    // Wt_s[o*52 + t*4 + h] = W[(t*4+h)*12 + o]
    for (int i = tid; i < OO * WTS; i += 192) {
        int o = i / WTS, col = i - o * WTS;
        if (col < TH) Wt_s[i] = W[col * OO + o];
    }
    if (tid < OO) bias_s[tid] = bias[tid];
    if (tid < NPB * KK) {
        int nl = tid >> 4, k = tid & 15;
        nbroff_s[nl][k] = nbrs[(n0 + nl) * KK + k] * (JJ * (int)sizeof(float4));
        float d = dists[(n0 + nl) * KK + k];
        float p = expf(-(d * d) * (1.0f / 144.0f));   // head h uses p^(h+1)
        float4 wv;
        wv.x = p;
        wv.y = p * p;
        wv.z = wv.y * p;
        wv.w = wv.y * wv.y;
        w4_s[nl][k] = wv;
    }
    __syncthreads();

    // ---- phase A: gather (384 B contiguous rows) + head-weighted aggregate --
    {
        const int nl  = tid / JJ;            // 0..7
        const int j   = tid - nl * JJ;       // 0..23
        const int b_l = j / Tin;             // 0..1
        const int t   = j - b_l * Tin;       // 0..11
        const char* xgb = (const char*)xT2 + (size_t)g * (NN * JJ * sizeof(float4));
        const unsigned j16 = (unsigned)j * 16u;

        // packed-pair accumulators (lo = ch0,1 / hi = ch2,3) per head
        f2 a0l = {0,0}, a0h = {0,0}, a1l = {0,0}, a1h = {0,0};
        f2 a2l = {0,0}, a2h = {0,0}, a3l = {0,0}, a3h = {0,0};
        #pragma unroll
        for (int k = 0; k < KK; k++) {
            unsigned off = (unsigned)nbroff_s[nl][k] + j16;
            float4 xv = *(const float4*)(xgb + off);
            f2 xl = {xv.x, xv.y}, xh = {xv.z, xv.w};
            float4 wv = w4_s[nl][k];
            f2 w0 = {wv.x, wv.x}, w1 = {wv.y, wv.y};
            f2 w2 = {wv.z, wv.z}, w3 = {wv.w, wv.w};
            a0l += w0 * xl; a0h += w0 * xh;
            a1l += w1 * xl; a1h += w1 * xh;
            a2l += w2 * xl; a2h += w2 * xh;
            a3l += w3 * xl; a3h += w3 * xh;
        }
        const int base = nl * FSN2 + b_l * FSB2 + t;    // + h*12
        feat[base +  0] = float4{a0l.x, a0l.y, a0h.x, a0h.y};
        feat[base + 12] = float4{a1l.x, a1l.y, a1h.x, a1h.y};
        feat[base + 24] = float4{a2l.x, a2l.y, a2h.x, a2h.y};
        feat[base + 36] = float4{a3l.x, a3l.y, a3h.x, a3h.y};
    }
    __syncthreads();

    // ---- phase B: (48 -> 12) GEMM, 1 wave, 3 outputs/thread ----
    // Block-level feat-read issues: 48 (vs 144 with per-o threads).
    if (tid < 64) {
        const int nl   = tid & 7;            // 0..7
        const int rest = tid >> 3;           // 0..7
        const int b_l  = rest & 1;           // 0..1
        const int o3   = rest >> 1;          // 0..3 -> o = 3*o3 + {0,1,2}
        const int o0   = 3 * o3;

        float4 acc[3];
        #pragma unroll
        for (int i = 0; i < 3; i++) {
            float bz = bias_s[o0 + i];
            acc[i] = float4{bz, bz, bz, bz};
        }
        const int fb = nl * FSN2 + b_l * FSB2;
        #pragma unroll
        for (int t = 0; t < Tin; t++) {
            float4 f0 = feat[fb + t];            // h=0
            float4 f1 = feat[fb + 12 + t];       // h=1
            float4 fq = feat[fb + 24 + t];       // h=2
            float4 f3 = feat[fb + 36 + t];       // h=3
            f2 f0l = {f0.x, f0.y}, f0h = {f0.z, f0.w};
            f2 f1l = {f1.x, f1.y}, f1h = {f1.z, f1.w};
            f2 f2l = {fq.x, fq.y}, f2h = {fq.z, fq.w};
            f2 f3l = {f3.x, f3.y}, f3h = {f3.z, f3.w};
            #pragma unroll
            for (int i = 0; i < 3; i++) {
                const float4 wq = *(const float4*)&Wt_s[(o0 + i) * WTS + t * 4];
                f2 al = {acc[i].x, acc[i].y}, ah = {acc[i].z, acc[i].w};
                f2 wx = {wq.x, wq.x}, wy = {wq.y, wq.y};
                f2 wz = {wq.z, wq.z}, ww = {wq.w, wq.w};
                al += wx * f0l; ah += wx * f0h;
                al += wy * f1l; ah += wy * f1h;
                al += wz * f2l; ah += wz * f2h;
                al += ww * f3l; ah += ww * f3h;
                acc[i] = float4{al.x, al.y, ah.x, ah.y};
            }
        }
        const int b = g * 2 + b_l;
        #pragma unroll
        for (int i = 0; i < 3; i++) {
            int o = o0 + i;
            float4 y = acc[i];
            y.x = fmaxf(y.x, 0.0f); y.y = fmaxf(y.y, 0.0f);
            y.z = fmaxf(y.z, 0.0f); y.w = fmaxf(y.w, 0.0f);
            nt_store4(y, &out4[(size_t)(b * Ttot + Tin + o) * NN + n0 + nl]);
        }
    }
}

extern "C" void kernel_launch(void* const* d_in, const int* in_sizes, int n_in,
                              void* d_out, int out_size, void* d_ws, size_t ws_size,
                              hipStream_t stream) {
    const float* x     = (const float*)d_in[0];
    const float* dists = (const float*)d_in[1];
    const float* W     = (const float*)d_in[2];
    const float* bias  = (const float*)d_in[3];
    const int*   nbrs  = (const int*)d_in[4];
    float4* out4 = (float4*)d_out;
    float4* xT2  = (float4*)d_ws;     // G*NN*JJ*16 B = 15.36 MB of ws

    dim3 g1((NN + K1_NB - 1) / K1_NB, G);          // (79, 8)
    hipLaunchKernelGGL(transpose_concat_kernel, g1, dim3(256), 0, stream,
                       (const float4*)x, xT2, out4);

    hipLaunchKernelGGL(gnn_main_kernel, dim3((NN / NPB) * G), dim3(192), 0, stream,
                       (const float4*)xT2, dists, W, bias, nbrs, out4);
}